// Round 1
// baseline (209.876 us; speedup 1.0000x reference)
//
#include <hip/hip_runtime.h>
#include <hip/hip_bf16.h>
#include <stdint.h>

#define Bn 8
#define Sn 4096
#define Hn 768
#define Dn 1024
#define Wn 2048

typedef __attribute__((ext_vector_type(8))) short short8;
typedef __attribute__((ext_vector_type(4))) short short4v;
typedef __attribute__((ext_vector_type(4))) float floatx4;

__device__ __forceinline__ void load_lds16(const void* g, void* l) {
  __builtin_amdgcn_global_load_lds(
      (const __attribute__((address_space(1))) void*)g,
      (__attribute__((address_space(3))) void*)l, 16, 0, 0);
}

// -------- kernel 1: fused prep --------------------------------------------------
// blocks [0, 768): transpose proj_w (H x D fp32) -> B^T (D x H bf16), 32x32 tiles
// blocks [768, 896): boundary table starts[b][w] from sorted word_ids
__global__ __launch_bounds__(256) void k_prep(const float* __restrict__ pw,
                                              const int* __restrict__ wid,
                                              __hip_bfloat16* __restrict__ wb,
                                              int* __restrict__ starts) {
  if (blockIdx.x < 768) {
    __shared__ float tile[32][33];
    const int bt = blockIdx.x;            // 32 x 24 tile grid
    const int d0 = (bt % 32) * 32, h0 = (bt / 32) * 32;
    const int tx = threadIdx.x & 31, ty = threadIdx.x >> 5;  // 32 x 8
#pragma unroll
    for (int i = 0; i < 32; i += 8)
      tile[ty + i][tx] = pw[(size_t)(h0 + ty + i) * Dn + d0 + tx];
    __syncthreads();
#pragma unroll
    for (int i = 0; i < 32; i += 8)
      wb[(size_t)(d0 + ty + i) * Hn + h0 + tx] = (__hip_bfloat16)tile[tx][ty + i];
  } else {
    const int bid = blockIdx.x - 768;       // 128 blocks cover (Bn, Sn)
    const int g = bid * 256 + threadIdx.x;  // 0 .. 32767
    const int b = g >> 12, s = g & (Sn - 1);
    const int* wbi = wid + (size_t)b * Sn;
    int* sb = starts + b * (Wn + 1);
    const int cur = wbi[s];
    const int prev = (s == 0) ? -1 : wbi[s - 1];
    for (int ww = prev + 1; ww <= cur; ++ww) sb[ww] = s;
    if (s == Sn - 1)
      for (int ww = cur + 1; ww <= Wn; ++ww) sb[ww] = Sn;
  }
}

// ------------- kernel 2: segment mean + validity mask ---------------------------
// One wave per word (4 words per 256-thread block). 4096 blocks -> 8 blocks/CU,
// 32 waves/CU in flight: this grid size IS the latency hiding (R4's 512-block
// variant regressed 4x on outstanding loads — do not shrink the grid).
__global__ __launch_bounds__(256) void k_words(const float* __restrict__ emb,
                                               const int* __restrict__ masks,
                                               const int* __restrict__ starts,
                                               __hip_bfloat16* __restrict__ wa,
                                               float* __restrict__ out_masks) {
  const int b = blockIdx.y;
  const int wave = threadIdx.x >> 6, lane = threadIdx.x & 63;
  const int w = blockIdx.x * 4 + wave;

  const int* sb = starts + b * (Wn + 1);
  const int start = sb[w];
  const int end = sb[w + 1];
  const int count = end - start;

  // parallel all-ones mask check (one 64-lane load per 64 subwords)
  const int* mb = masks + (size_t)b * Sn;
  bool allone = true;
  for (int s0 = start; s0 < end; s0 += 64) {
    const int idx = s0 + lane;
    allone = allone && ((idx < end) ? (mb[idx] == 1) : true);
  }
  const bool valid = (count > 0) && __all(allone);
  const float inv = valid ? 1.0f / (float)count : 0.0f;

  floatx4 sum[3] = {{0.f, 0.f, 0.f, 0.f}, {0.f, 0.f, 0.f, 0.f}, {0.f, 0.f, 0.f, 0.f}};
  const float* eb = emb + (size_t)b * Sn * Hn;
  int s = start;
  for (; s + 1 < end; s += 2) {
    const floatx4* r0 = (const floatx4*)(eb + (size_t)s * Hn);
    const floatx4* r1 = (const floatx4*)(eb + (size_t)(s + 1) * Hn);
#pragma unroll
    for (int j = 0; j < 3; ++j) sum[j] += r0[j * 64 + lane];
#pragma unroll
    for (int j = 0; j < 3; ++j) sum[j] += r1[j * 64 + lane];
  }
  if (s < end) {
    const floatx4* r0 = (const floatx4*)(eb + (size_t)s * Hn);
#pragma unroll
    for (int j = 0; j < 3; ++j) sum[j] += r0[j * 64 + lane];
  }

  const size_t rowbase = ((size_t)b * Wn + w) * Hn;
#pragma unroll
  for (int j = 0; j < 3; ++j) {
    short4v o;
#pragma unroll
    for (int c = 0; c < 4; ++c) {
      __hip_bfloat16 h = (__hip_bfloat16)(sum[j][c] * inv);
      o[c] = *reinterpret_cast<short*>(&h);
    }
    *(short4v*)&wa[rowbase + (size_t)(j * 64 + lane) * 4] = o;
  }
  if (lane == 0) out_masks[(size_t)b * Wn + w] = valid ? 1.0f : 0.0f;
}

// ------------- kernel 3: bf16 MFMA GEMM  C = A @ B^T + bias ---------------------
// A: (M=16384, K=768) bf16, Bt: (N=1024, K=768) bf16, C fp32.
// Deep-pipelined template (T2+T3+T4+T5):
//   * 256x128 tile, BK=64, 512 threads = 8 waves (4M x 2N), 64x64 out per wave.
//   * 3-buffer LDS ring (A 32K + B 16K = 48 KiB/tile, 144 KiB total): compute
//     tile t from slot t%3 while staging tile t+2 into slot (t+2)%3 -- no LDS
//     buffer is ever read and written concurrently, by construction.
//   * Counted s_waitcnt vmcnt(6) once per K-tile (6 stage loads/thread/tile):
//     tile t+2's loads stay in flight across barriers, tile t+1 guaranteed
//     landed (T4 -- the m218 lever). Peeled tail tiles drain with vmcnt(0).
//   * XOR swizzle slot^=(row&7), applied on BOTH the pre-swizzled global
//     source of global_load_lds and the ds_read address (rule 21): kills the
//     8-way bank aliasing of [row][64-short] fragment reads (T2).
//   * raw s_barrier + explicit lgkmcnt(0)+sched_barrier(0) (rule 18),
//     s_setprio around each 16-MFMA cluster (T5).
constexpr int GK = Hn;                 // 768
constexpr int LDS_A = 256 * 64;        // shorts per A tile buffer
constexpr int LDS_B = 128 * 64;        // shorts per B tile buffer
constexpr int LDS_T = LDS_A + LDS_B;   // 24576 shorts = 48 KiB per ring slot

__global__ __launch_bounds__(512, 2) void k_gemm(const short* __restrict__ A,
                                                 const short* __restrict__ Bt,
                                                 const float* __restrict__ bias,
                                                 float* __restrict__ out) {
  extern __shared__ __align__(16) short ls[];  // 3 * LDS_T shorts = 144 KiB

  const int t = threadIdx.x;  // 0..511
  const int lane = t & 63;
  const int wave = t >> 6;
  const int wm = wave >> 1, wn = wave & 1;        // 4 x 2 wave grid
  const int lane16 = lane & 15, quad = lane >> 4;
  const int swz = lane16 & 7;

  // grid: 512 blocks = 8 XCDs x (8 m-tiles x 8 n-tiles), n fastest so each
  // XCD's 2048-row A strip (3 MiB) stays L2-resident across its 8 n-tiles.
  const int linear = blockIdx.x;
  const int xcd = linear & 7;
  const int o = linear >> 3;  // 0..63
  const int m0 = (xcd * 8 + (o >> 3)) * 256;
  const int n0 = (o & 7) * 128;

  // staging: thread t covers row rA of each 64-row chunk, physical 16B slot
  // t&7; pre-swizzled global column slot = (t&7) ^ (row&7)  (involution).
  const int rA = t >> 3;
  const int ssw = ((t & 7) ^ (rA & 7)) * 8;  // shorts
  const short* gAs = A + (size_t)(m0 + rA) * GK + ssw;
  const short* gBs = Bt + (size_t)(n0 + rA) * GK + ssw;

  auto stage_a3 = [&](int slot, int tt) {  // A chunks j=0,1,2
    short* d = ls + slot * LDS_T + t * 8;
    const short* g = gAs + tt * 64;
    load_lds16(g, d);
    load_lds16(g + (size_t)64 * GK, d + 4096);
    load_lds16(g + (size_t)128 * GK, d + 8192);
  };
  auto stage_b3 = [&](int slot, int tt) {  // A chunk j=3, B chunks j=0,1
    short* d = ls + slot * LDS_T + t * 8;
    load_lds16(gAs + tt * 64 + (size_t)192 * GK, d + 12288);
    load_lds16(gBs + tt * 64, d + 16384);
    load_lds16(gBs + tt * 64 + (size_t)64 * GK, d + 20480);
  };

  auto ld_af = [&](short8 (&af)[2][2], int mib, const short* bufA) {
#pragma unroll
    for (int m2 = 0; m2 < 2; ++m2)
#pragma unroll
      for (int ks = 0; ks < 2; ++ks)
        af[m2][ks] = *(const short8*)&bufA[(wm * 64 + (mib + m2) * 16 + lane16) * 64 +
                                           ((((ks << 2) | quad) ^ swz) << 3)];
  };
  auto ld_bf = [&](short8 (&bf)[4][2], const short* bufB) {
#pragma unroll
    for (int ni = 0; ni < 4; ++ni)
#pragma unroll
      for (int ks = 0; ks < 2; ++ks)
        bf[ni][ks] = *(const short8*)&bufB[(wn * 64 + ni * 16 + lane16) * 64 +
                                           ((((ks << 2) | quad) ^ swz) << 3)];
  };

  floatx4 acc[4][4];
#pragma unroll
  for (int i = 0; i < 4; ++i)
#pragma unroll
    for (int j = 0; j < 4; ++j) acc[i][j] = (floatx4){0.f, 0.f, 0.f, 0.f};

  auto mmac2 = [&](short8 (&af)[2][2], short8 (&bf)[4][2], int mib) {
    __builtin_amdgcn_s_setprio(1);
#pragma unroll
    for (int m2 = 0; m2 < 2; ++m2)
#pragma unroll
      for (int ni = 0; ni < 4; ++ni)
#pragma unroll
        for (int ks = 0; ks < 2; ++ks)
          acc[mib + m2][ni] = __builtin_amdgcn_mfma_f32_16x16x32_bf16(
              af[m2][ks], bf[ni][ks], acc[mib + m2][ni], 0, 0, 0);
    __builtin_amdgcn_s_setprio(0);
  };

  // prologue: stage tiles 0 and 1 (12 loads); vmcnt(6) -> tile 0 landed.
  stage_a3(0, 0);
  stage_b3(0, 0);
  stage_a3(1, 1);
  stage_b3(1, 1);
  asm volatile("s_waitcnt vmcnt(6)" ::: "memory");
  __builtin_amdgcn_sched_barrier(0);
  __builtin_amdgcn_s_barrier();

  int cur = 0;
#pragma unroll 1
  for (int tt = 0; tt < 12; ++tt) {  // 12 K-tiles of 64
    const short* bufA = ls + cur * LDS_T;
    const short* bufB = bufA + LDS_A;
    const int nx2 = (cur + 2 >= 3) ? cur - 1 : cur + 2;  // (tt+2)%3
    const bool st = tt < 10;                             // stage tiles 2..11
    short8 af[2][2], bf[4][2];

    // ---- phase A: mi 0,1 ----
    ld_af(af, 0, bufA);
    ld_bf(bf, bufB);
    if (st) stage_a3(nx2, tt + 2);
    __builtin_amdgcn_s_barrier();
    asm volatile("s_waitcnt lgkmcnt(0)" ::: "memory");
    __builtin_amdgcn_sched_barrier(0);
    mmac2(af, bf, 0);
    __builtin_amdgcn_s_barrier();

    // ---- phase B: mi 2,3 (bf reused in registers) ----
    ld_af(af, 2, bufA);
    if (st) stage_b3(nx2, tt + 2);
    if (tt < 10) {
      // counted: keep tile tt+2's 6 loads in flight, tile tt+1 landed
      asm volatile("s_waitcnt vmcnt(6)" ::: "memory");
    } else if (tt == 10) {
      // tail: nothing new issued; drain so tile 11 is resident
      asm volatile("s_waitcnt vmcnt(0)" ::: "memory");
    }
    __builtin_amdgcn_sched_barrier(0);
    __builtin_amdgcn_s_barrier();
    asm volatile("s_waitcnt lgkmcnt(0)" ::: "memory");
    __builtin_amdgcn_sched_barrier(0);
    mmac2(af, bf, 2);
    __builtin_amdgcn_s_barrier();

    cur = (cur + 1 == 3) ? 0 : cur + 1;
  }

  // epilogue: bias loaded here (keeps the loop's vmcnt counting exact).
  float bv[4];
#pragma unroll
  for (int ni = 0; ni < 4; ++ni) bv[ni] = bias[n0 + wn * 64 + ni * 16 + lane16];

  // C/D layout: col = lane&15, row = quad*4 + r (m89/m91-verified)
#pragma unroll
  for (int mi = 0; mi < 4; ++mi) {
#pragma unroll
    for (int ni = 0; ni < 4; ++ni) {
      const int n = n0 + wn * 64 + ni * 16 + lane16;
#pragma unroll
      for (int r = 0; r < 4; ++r) {
        const int m = m0 + wm * 64 + mi * 16 + quad * 4 + r;
        out[(size_t)m * Dn + n] = acc[mi][ni][r] + bv[ni];
      }
    }
  }
}

extern "C" void kernel_launch(void* const* d_in, const int* in_sizes, int n_in,
                              void* d_out, int out_size, void* d_ws, size_t ws_size,
                              hipStream_t stream) {
  const float* emb    = (const float*)d_in[0];  // (8, 4096, 768)
  const float* proj_w = (const float*)d_in[1];  // (768, 1024)
  const float* proj_b = (const float*)d_in[2];  // (1024,)
  const int*   masks  = (const int*)d_in[3];    // (8, 4096)
  const int*   wid    = (const int*)d_in[4];    // (8, 4096)

  float* out = (float*)d_out;                       // (8, 2048, 1024) fp32
  float* out_masks = out + (size_t)Bn * Wn * Dn;    // (8, 2048) as 0.0/1.0

  __hip_bfloat16* wb = (__hip_bfloat16*)d_ws;            // B^T: (1024, 768) bf16
  __hip_bfloat16* wa = wb + (size_t)Dn * Hn;             // A:   (16384, 768) bf16
  int* starts = (int*)(wa + (size_t)Bn * Wn * Hn);       // (8, 2049) boundaries

  // 1. fused: transpose proj_w + boundary table
  k_prep<<<dim3(768 + (Bn * Sn) / 256), 256, 0, stream>>>(proj_w, wid, wb, starts);

  // 2. segment means + masks (one wave per word)
  k_words<<<dim3(Wn / 4, Bn), 256, 0, stream>>>(emb, masks, starts, wa, out_masks);

  // 3. projection GEMM + bias: 256x128 tiles, 3-buffer ring, counted vmcnt.
  constexpr int kGemmLds = 3 * LDS_T * (int)sizeof(short);  // 147456 B
  static_assert(kGemmLds == 147456, "LDS budget");
  (void)hipFuncSetAttribute((const void*)k_gemm,
                            hipFuncAttributeMaxDynamicSharedMemorySize, kGemmLds);
  k_gemm<<<dim3(512), 512, kGemmLds, stream>>>((const short*)wa, (const short*)wb,
                                               proj_b, out);
}